// Round 6
// baseline (201.224 us; speedup 1.0000x reference)
//
#include <hip/hip_runtime.h>

// ---------------------------------------------------------------------------
// MultiHeadedAttention: x[8,1024,768] @ w_in[768,2304] -> qkv -> 12-head attn
// (scale = 768^-0.5) -> concat -> @ w_out[768,768] + b_out. f32 in/out,
// bf16 MFMA internally. GEMM: BK=64 2-phase gload_lds dbuf (32 MFMA/barrier).
// Attn: swapped QK^T + k-perm PV (P in regs); V read direct from XCD-L2
// (no LDS staging, m169 lesson); lazy max / deferred l reduction.
// ---------------------------------------------------------------------------

using short8 = __attribute__((ext_vector_type(8))) short;  // 8 bf16 (4 VGPR)
using s16x4  = __attribute__((ext_vector_type(4))) short;  // 4 bf16 (b64)
using f32x4  = __attribute__((ext_vector_type(4))) float;  // MFMA acc

#define MFMA_B16(a, b, c) __builtin_amdgcn_mfma_f32_16x16x32_bf16((a), (b), (c), 0, 0, 0)

typedef const __attribute__((address_space(1))) void* gvoid_p;
typedef __attribute__((address_space(3))) void* lvoid_p;

constexpr int   kDim   = 768;
constexpr int   kHeads = 12;
constexpr int   kSeq   = 1024;
constexpr float kScale = 0.03608439182435161f;             // 768^-0.5 (full dim)
constexpr float kQSc   = kScale * 1.4426950408889634f;     // fold log2(e) into Q

__device__ __forceinline__ short f2bf(float f) {  // RNE f32 -> bf16 bits
  unsigned u = __float_as_uint(f);
  u += 0x7FFFu + ((u >> 16) & 1u);
  return (short)(u >> 16);
}
__device__ __forceinline__ unsigned cvt_pk_bf16(float lo, float hi) {
  unsigned r;
  asm("v_cvt_pk_bf16_f32 %0, %1, %2" : "=v"(r) : "v"(lo), "v"(hi));
  return r;
}
union U8 { unsigned u[4]; short8 s; };

// ---------- x: f32 -> bf16 cast ---------------------------------------------
__global__ __launch_bounds__(256) void cvt_f32_bf16(const float* __restrict__ in,
                                                    short* __restrict__ out) {
  const int i = blockIdx.x * 256 + threadIdx.x;  // one short8 per thread
  float4 a = ((const float4*)in)[i * 2];
  float4 b = ((const float4*)in)[i * 2 + 1];
  short8 s;
  s[0] = f2bf(a.x); s[1] = f2bf(a.y); s[2] = f2bf(a.z); s[3] = f2bf(a.w);
  s[4] = f2bf(b.x); s[5] = f2bf(b.y); s[6] = f2bf(b.z); s[7] = f2bf(b.w);
  ((short8*)out)[i] = s;
}

// ---------- transpose + convert: out[c][r] = bf16(in[r][c]) ----------------
__global__ __launch_bounds__(256) void transpose_cvt(const float* __restrict__ in,
                                                     short* __restrict__ out,
                                                     int R, int C) {
  __shared__ float tile[32][33];
  const int c0 = blockIdx.x * 32, r0 = blockIdx.y * 32;
  const int tx = threadIdx.x & 31, ty = threadIdx.x >> 5;
#pragma unroll
  for (int i = 0; i < 32; i += 8)
    tile[ty + i][tx] = in[(size_t)(r0 + ty + i) * C + c0 + tx];
  __syncthreads();
#pragma unroll
  for (int i = 0; i < 32; i += 8)
    out[(size_t)(c0 + ty + i) * R + r0 + tx] = f2bf(tile[tx][ty + i]);
}

// ---------- 128x128 MFMA GEMM, BK=64, 4 waves, 2-phase gload_lds dbuf ------
// 32 MFMA + 16 ds_read_b128 per barrier pair (2x the BK=32 version) to
// amortize the vmcnt(0)+barrier drain. LDS 64 KiB -> 2 blocks/CU.
template <int EPI>
__global__ __launch_bounds__(256) void gemm_tile(const short* __restrict__ A,
                                                 const short* __restrict__ BT,
                                                 int Kd,
                                                 short* __restrict__ Qb,
                                                 short* __restrict__ Kb,
                                                 short* __restrict__ VTb,
                                                 const float* __restrict__ bias,
                                                 float* __restrict__ outF) {
  __shared__ short As[2][128 * 64];
  __shared__ short Bs[2][128 * 64];

  const int tid  = threadIdx.x;
  const int lane = tid & 63, w = tid >> 6;
  const int L = lane & 15, g = lane >> 4;
  const int wr = w >> 1, wc = w & 1;
  const int m0 = blockIdx.x * 128, n0 = blockIdx.y * 128;

  const int r8 = lane >> 3;        // 0..7: row within 8-row chunk
  const int c8 = (lane & 7) * 8;   // k-col (shorts)

  // wave w stages rows w*32..w*32+31 of each [128][64] tile, 4 chunks of 8
  // rows; gload_lds dest is wave-uniform base + lane*16B (linear layout).
  auto stage = [&](int buf, int k0) {
#pragma unroll
    for (int c = 0; c < 4; ++c) {
      const int row = w * 32 + c * 8;
      const short* ag = A  + (size_t)(m0 + row + r8) * Kd + k0 + c8;
      const short* bg = BT + (size_t)(n0 + row + r8) * Kd + k0 + c8;
      __builtin_amdgcn_global_load_lds((gvoid_p)ag, (lvoid_p)&As[buf][row * 64], 16, 0, 0);
      __builtin_amdgcn_global_load_lds((gvoid_p)bg, (lvoid_p)&Bs[buf][row * 64], 16, 0, 0);
    }
  };

  f32x4 acc[4][4] = {};

  stage(0, 0);
  __syncthreads();  // vmcnt(0) drain: tile 0 ready

  const int NT = Kd / 64;
  for (int t = 0; t < NT; ++t) {
    const int cur = t & 1;
    if (t + 1 < NT) stage(cur ^ 1, (t + 1) * 64);  // in flight during compute

    short8 af[2][4], bfr[2][4];
#pragma unroll
    for (int kk = 0; kk < 2; ++kk) {
#pragma unroll
      for (int mi = 0; mi < 4; ++mi)
        af[kk][mi] = *(const short8*)&As[cur][(wr * 64 + mi * 16 + L) * 64 + kk * 32 + g * 8];
#pragma unroll
      for (int ni = 0; ni < 4; ++ni)
        bfr[kk][ni] = *(const short8*)&Bs[cur][(wc * 64 + ni * 16 + L) * 64 + kk * 32 + g * 8];
    }
#pragma unroll
    for (int kk = 0; kk < 2; ++kk)
#pragma unroll
      for (int mi = 0; mi < 4; ++mi)
#pragma unroll
        for (int ni = 0; ni < 4; ++ni)
          acc[mi][ni] = MFMA_B16(af[kk][mi], bfr[kk][ni], acc[mi][ni]);

    __syncthreads();  // drains vmcnt (prefetch landed) + lgkm; reuse-safe
  }

  if (EPI == 0) {
    const int t3 = n0 / kDim;  // 0:Q 1:K 2:V (uniform per block; 768 = 6*128)
#pragma unroll
    for (int mi = 0; mi < 4; ++mi) {
#pragma unroll
      for (int ni = 0; ni < 4; ++ni) {
        const int gcol = n0 + wc * 64 + ni * 16 + L;
        const int hd = gcol % kDim;
        const int h = hd >> 6, d = hd & 63;
        if (t3 == 2) {  // V^T: 4 r-values are contiguous seq -> one 8B store
          const int grow = m0 + wr * 64 + mi * 16 + 4 * g;
          const int b = grow >> 10, seq = grow & 1023;
          const int bh = b * kHeads + h;
          uint2 d2;
          d2.x = cvt_pk_bf16(acc[mi][ni][0], acc[mi][ni][1]);
          d2.y = cvt_pk_bf16(acc[mi][ni][2], acc[mi][ni][3]);
          *(uint2*)&VTb[((size_t)bh * 64 + d) * kSeq + seq] = d2;
        } else {
#pragma unroll
          for (int r = 0; r < 4; ++r) {
            const int grow = m0 + wr * 64 + mi * 16 + 4 * g + r;  // b*1024+seq
            const int b = grow >> 10, seq = grow & 1023;
            const int bh = b * kHeads + h;
            if (t3 == 0) Qb[((size_t)bh * kSeq + seq) * 64 + d] = f2bf(acc[mi][ni][r] * kQSc);
            else         Kb[((size_t)bh * kSeq + seq) * 64 + d] = f2bf(acc[mi][ni][r]);
          }
        }
      }
    }
  } else {
#pragma unroll
    for (int ni = 0; ni < 4; ++ni) {
      const int gcol = n0 + wc * 64 + ni * 16 + L;
      const float bv = bias[gcol];
#pragma unroll
      for (int mi = 0; mi < 4; ++mi) {
#pragma unroll
        for (int r = 0; r < 4; ++r) {
          const int grow = m0 + wr * 64 + mi * 16 + 4 * g + r;
          outF[(size_t)grow * kDim + gcol] = acc[mi][ni][r] + bv;
        }
      }
    }
  }
}

// ---------- flash attention v6 ----------------------------------------------
// Swapped QK^T + k-perm PV (P in regs), lazy max-reduce, deferred l-reduce.
// NEW: V is NOT staged in LDS — with the XCD-grouped grid, V is L2-resident;
// k-perm B-fragments load directly from global (16x 8B, hoisted before the
// softmax so L2 latency hides under exp2). LDS: K double-buffer only (18 KiB).
__global__ __launch_bounds__(256) void attn_kernel(const short* __restrict__ Qb,
                                                   const short* __restrict__ Kb,
                                                   const short* __restrict__ VTb,
                                                   short* __restrict__ AO) {
  __shared__ short Ks[2][64 * 72];   // [key][d]

  const int tid  = threadIdx.x;
  const int lane = tid & 63, w = tid >> 6;
  const int L = lane & 15, g = lane >> 4;
  const int id = blockIdx.x;
  const int bh = id % 96, qc = id / 96;
  const int q0 = qc * 128 + w * 32;

  const short* Qbase = Qb  + (size_t)bh * kSeq * 64;
  const short* Kbase = Kb  + (size_t)bh * kSeq * 64;
  const short* Vbase = VTb + (size_t)bh * 64 * kSeq;

  short8 qf[2][2];  // Q (pre-scaled by kQSc) as B-operand, resident in regs
#pragma unroll
  for (int qh = 0; qh < 2; ++qh) {
    const short* qp = Qbase + (size_t)(q0 + qh * 16 + L) * 64 + g * 8;
    qf[qh][0] = *(const short8*)qp;
    qf[qh][1] = *(const short8*)(qp + 32);
  }

  f32x4 o[2][4] = {};
  float m_[2] = {-1e30f, -1e30f};  // per-query running max (replicated over g)
  float l_[2] = {0.f, 0.f};        // per-LANE partial sum (reduced at end)

  const int srow = tid >> 2, sc0 = (tid & 3) * 16;  // K staging: 16 elem/thr

  {  // prologue: stage K tile 0
    const short* ksrc = Kbase + (size_t)srow * 64 + sc0;
    uint4 k0 = ((const uint4*)ksrc)[0], k1 = ((const uint4*)ksrc)[1];
    *(uint4*)&Ks[0][srow * 72 + sc0]     = k0;
    *(uint4*)&Ks[0][srow * 72 + sc0 + 8] = k1;
  }
  __syncthreads();

  for (int t = 0; t < kSeq / 64; ++t) {
    const int cur = t & 1;
    const int kv0 = t * 64;
    const bool pf = (t + 1 < kSeq / 64);

    // ---- issue next K-tile loads early (T14 async split) ----
    uint4 kr0, kr1;
    if (pf) {
      const short* ksrc = Kbase + (size_t)(kv0 + 64 + srow) * 64 + sc0;
      kr0 = ((const uint4*)ksrc)[0];
      kr1 = ((const uint4*)ksrc)[1];
    }

    // ---- K fragments (A-operand) from LDS ----
    short8 kf[4][2];
#pragma unroll
    for (int nf = 0; nf < 4; ++nf) {
      const short* kp = &Ks[cur][(nf * 16 + L) * 72 + g * 8];
      kf[nf][0] = *(const short8*)kp;
      kf[nf][1] = *(const short8*)(kp + 32);
    }
    // ---- V fragments (k-perm B-operand) DIRECT FROM GLOBAL (L2-hot);
    //      issued here so ~200cy L2 latency hides under softmax VALU ----
    short8 vb[4][2];
#pragma unroll
    for (int nf = 0; nf < 4; ++nf) {
      const short* vrow = Vbase + (size_t)(nf * 16 + L) * kSeq + kv0;
      s16x4 a0 = *(const s16x4*)&vrow[4 * g];
      s16x4 a1 = *(const s16x4*)&vrow[16 + 4 * g];
      s16x4 a2 = *(const s16x4*)&vrow[32 + 4 * g];
      s16x4 a3 = *(const s16x4*)&vrow[48 + 4 * g];
      vb[nf][0] = __builtin_shufflevector(a0, a1, 0, 1, 2, 3, 4, 5, 6, 7);
      vb[nf][1] = __builtin_shufflevector(a2, a3, 0, 1, 2, 3, 4, 5, 6, 7);
    }

    short8 pa[2][2];
#pragma unroll
    for (int qh = 0; qh < 2; ++qh) {
      // ---- S^T = K @ Q^T: lane holds S[key=nf*16+4g+r][query=L] ----
      f32x4 s[4];
      __builtin_amdgcn_s_setprio(1);
#pragma unroll
      for (int nf = 0; nf < 4; ++nf) {
        f32x4 z = {};
        z = MFMA_B16(kf[nf][0], qf[qh][0], z);
        s[nf] = MFMA_B16(kf[nf][1], qf[qh][1], z);
      }
      __builtin_amdgcn_s_setprio(0);

      // ---- lazy defer-max: per-lane max only; no cross-lane on common path
      float x0 = fmaxf(fmaxf(s[0][0], s[0][1]), fmaxf(s[0][2], s[0][3]));
      float x1 = fmaxf(fmaxf(s[1][0], s[1][1]), fmaxf(s[1][2], s[1][3]));
      float x2 = fmaxf(fmaxf(s[2][0], s[2][1]), fmaxf(s[2][2], s[2][3]));
      float x3 = fmaxf(fmaxf(s[3][0], s[3][1]), fmaxf(s[3][2], s[3][3]));
      const float mt4 = fmaxf(fmaxf(x0, x1), fmaxf(x2, x3));

      if (__any(mt4 > m_[qh] + 8.0f)) {  // wave-uniform branch (rare)
        float mt = fmaxf(mt4, __shfl_xor(mt4, 16, 64));
        mt = fmaxf(mt, __shfl_xor(mt, 32, 64));          // per-query true max
        const float mnew = fmaxf(m_[qh], mt);
        const float al = __builtin_amdgcn_exp2f(m_[qh] - mnew);
        m_[qh] = mnew;
        l_[qh] *= al;  // per-lane partial: al is query-uniform across g
        float alr[4];
#pragma unroll
        for (int r = 0; r < 4; ++r) alr[r] = __shfl(al, 4 * g + r, 64);
#pragma unroll
        for (int nf = 0; nf < 4; ++nf)
#pragma unroll
          for (int r = 0; r < 4; ++r) o[qh][nf][r] *= alr[r];
      }

      // ---- p = exp2(s - m); lane-local sum; P packed in regs ----
      float rsum = 0.f;
#pragma unroll
      for (int nf = 0; nf < 4; ++nf) {
#pragma unroll
        for (int r = 0; r < 4; ++r) {
          const float p = __builtin_amdgcn_exp2f(s[nf][r] - m_[qh]);
          s[nf][r] = p;
          rsum += p;
        }
      }
      l_[qh] += rsum;  // per-lane partial

      U8 t0, t1;
      t0.u[0] = cvt_pk_bf16(s[0][0], s[0][1]);
      t0.u[1] = cvt_pk_bf16(s[0][2], s[0][3]);
      t0.u[2] = cvt_pk_bf16(s[1][0], s[1][1]);
      t0.u[3] = cvt_pk_bf16(s[1][2], s[1][3]);
      t1.u[0] = cvt_pk_bf16(s[2][0], s[2][1]);
      t1.u[1] = cvt_pk_bf16(s[2][2], s[2][3]);
      t1.u[2] = cvt_pk_bf16(s[3][0], s[3][1]);
      t1.u[3] = cvt_pk_bf16(s[3][2], s[3][3]);
      pa[qh][0] = t0.s;
      pa[qh][1] = t1.s;
    }

    // ---- O += P @ V ----
    __builtin_amdgcn_s_setprio(1);
#pragma unroll
    for (int nf = 0; nf < 4; ++nf) {
#pragma unroll
      for (int qh = 0; qh < 2; ++qh) {
        o[qh][nf] = MFMA_B16(pa[qh][0], vb[nf][0], o[qh][nf]);
        o[qh][nf] = MFMA_B16(pa[qh][1], vb[nf][1], o[qh][nf]);
      }
    }
    __builtin_amdgcn_s_setprio(0);

    // ---- write prefetched K tile into other buffer; one barrier per tile --
    if (pf) {
      *(uint4*)&Ks[cur ^ 1][srow * 72 + sc0]     = kr0;
      *(uint4*)&Ks[cur ^ 1][srow * 72 + sc0 + 8] = kr1;
    }
    __syncthreads();
  }

  // ---- finalize: reduce l across g-groups ONCE, O /= l, store ----
  const int b = bh / kHeads, h = bh % kHeads;
#pragma unroll
  for (int qh = 0; qh < 2; ++qh) {
    float ls = l_[qh] + __shfl_xor(l_[qh], 16, 64);
    ls += __shfl_xor(ls, 32, 64);  // full per-query sum
    float lq[4];
#pragma unroll
    for (int r = 0; r < 4; ++r) lq[r] = __shfl(ls, 4 * g + r, 64);
    short* aop = AO + ((size_t)(b * kSeq) + q0 + qh * 16) * kDim + h * 64;
#pragma unroll
    for (int r = 0; r < 4; ++r) {
      const float inv = 1.0f / lq[r];
#pragma unroll
      for (int nf = 0; nf < 4; ++nf)
        aop[(size_t)(4 * g + r) * kDim + nf * 16 + L] = f2bf(o[qh][nf][r] * inv);
    }
  }
}

// ---------------------------------------------------------------------------
extern "C" void kernel_launch(void* const* d_in, const int* in_sizes, int n_in,
                              void* d_out, int out_size, void* d_ws, size_t ws_size,
                              hipStream_t stream) {
  const float* x     = (const float*)d_in[0];
  const float* w_in  = (const float*)d_in[1];
  const float* w_out = (const float*)d_in[2];
  const float* b_out = (const float*)d_in[3];
  float* out = (float*)d_out;

  // workspace (bf16 as short). xbf aliases AO: xbf dead before attn writes AO.
  short* WinT  = (short*)d_ws;                          // [2304][768]
  short* WoutT = WinT  + (size_t)2304 * 768;            // [768][768]
  short* Qb    = WoutT + (size_t)768 * 768;             // [96][1024][64]
  short* Kb    = Qb    + (size_t)96 * 1024 * 64;        // [96][1024][64]
  short* VTb   = Kb    + (size_t)96 * 1024 * 64;        // [96][64][1024]
  short* AO    = VTb   + (size_t)96 * 1024 * 64;        // [8192][768]
  short* xbf   = AO;                                    // alias (see above)

  cvt_f32_bf16<<<dim3(8192 * 768 / (256 * 8)), 256, 0, stream>>>(x, xbf);
  transpose_cvt<<<dim3(2304 / 32, 768 / 32), 256, 0, stream>>>(w_in, WinT, 768, 2304);
  transpose_cvt<<<dim3(768 / 32, 768 / 32), 256, 0, stream>>>(w_out, WoutT, 768, 768);

  gemm_tile<0><<<dim3(8192 / 128, 2304 / 128), 256, 0, stream>>>(
      xbf, WinT, 768, Qb, Kb, VTb, nullptr, nullptr);

  attn_kernel<<<dim3(768), 256, 0, stream>>>(Qb, Kb, VTb, AO);

  gemm_tile<1><<<dim3(8192 / 128, 768 / 128), 256, 0, stream>>>(
      AO, WoutT, 768, nullptr, nullptr, nullptr, b_out, out);
}

// Round 7
// 126.391 us; speedup vs baseline: 1.5921x; 1.5921x over previous
//
#include <hip/hip_runtime.h>

// ---------------------------------------------------------------------------
// MultiHeadedAttention: x[8,1024,768] @ w_in[768,2304] -> qkv -> 12-head attn
// (scale = 768^-0.5) -> concat -> @ w_out[768,768] + b_out. f32 in/out,
// bf16 MFMA internally. R7 = R5 config (BK=32 GEMM, V staged in LDS) +
// attn QK-hoist: both q-halves' QK MFMAs issued back-to-back so qh1's MFMA
// latency hides under qh0's softmax VALU chain.
// ---------------------------------------------------------------------------

using short8 = __attribute__((ext_vector_type(8))) short;  // 8 bf16 (4 VGPR)
using s16x4  = __attribute__((ext_vector_type(4))) short;  // 4 bf16 (b64)
using f32x4  = __attribute__((ext_vector_type(4))) float;  // MFMA acc

#define MFMA_B16(a, b, c) __builtin_amdgcn_mfma_f32_16x16x32_bf16((a), (b), (c), 0, 0, 0)

typedef const __attribute__((address_space(1))) void* gvoid_p;
typedef __attribute__((address_space(3))) void* lvoid_p;

constexpr int   kDim   = 768;
constexpr int   kHeads = 12;
constexpr int   kSeq   = 1024;
constexpr float kScale = 0.03608439182435161f;             // 768^-0.5 (full dim)
constexpr float kQSc   = kScale * 1.4426950408889634f;     // fold log2(e) into Q

__device__ __forceinline__ short f2bf(float f) {  // RNE f32 -> bf16 bits
  unsigned u = __float_as_uint(f);
  u += 0x7FFFu + ((u >> 16) & 1u);
  return (short)(u >> 16);
}
__device__ __forceinline__ unsigned cvt_pk_bf16(float lo, float hi) {
  unsigned r;
  asm("v_cvt_pk_bf16_f32 %0, %1, %2" : "=v"(r) : "v"(lo), "v"(hi));
  return r;
}
union U8 { unsigned u[4]; short8 s; };

// ---------- x: f32 -> bf16 cast ---------------------------------------------
__global__ __launch_bounds__(256) void cvt_f32_bf16(const float* __restrict__ in,
                                                    short* __restrict__ out) {
  const int i = blockIdx.x * 256 + threadIdx.x;  // one short8 per thread
  float4 a = ((const float4*)in)[i * 2];
  float4 b = ((const float4*)in)[i * 2 + 1];
  short8 s;
  s[0] = f2bf(a.x); s[1] = f2bf(a.y); s[2] = f2bf(a.z); s[3] = f2bf(a.w);
  s[4] = f2bf(b.x); s[5] = f2bf(b.y); s[6] = f2bf(b.z); s[7] = f2bf(b.w);
  ((short8*)out)[i] = s;
}

// ---------- transpose + convert: out[c][r] = bf16(in[r][c]) ----------------
__global__ __launch_bounds__(256) void transpose_cvt(const float* __restrict__ in,
                                                     short* __restrict__ out,
                                                     int R, int C) {
  __shared__ float tile[32][33];
  const int c0 = blockIdx.x * 32, r0 = blockIdx.y * 32;
  const int tx = threadIdx.x & 31, ty = threadIdx.x >> 5;
#pragma unroll
  for (int i = 0; i < 32; i += 8)
    tile[ty + i][tx] = in[(size_t)(r0 + ty + i) * C + c0 + tx];
  __syncthreads();
#pragma unroll
  for (int i = 0; i < 32; i += 8)
    out[(size_t)(c0 + ty + i) * R + r0 + tx] = f2bf(tile[tx][ty + i]);
}

// ---------- 128x128 MFMA GEMM, BK=32, 4 waves, 2-phase gload_lds dbuf ------
template <int EPI>
__global__ __launch_bounds__(256) void gemm_tile(const short* __restrict__ A,
                                                 const short* __restrict__ BT,
                                                 int Kd,
                                                 short* __restrict__ Qb,
                                                 short* __restrict__ Kb,
                                                 short* __restrict__ VTb,
                                                 const float* __restrict__ bias,
                                                 float* __restrict__ outF) {
  __shared__ short As[2][128 * 32];
  __shared__ short Bs[2][128 * 32];

  const int tid  = threadIdx.x;
  const int lane = tid & 63, w = tid >> 6;
  const int L = lane & 15, g = lane >> 4;
  const int wr = w >> 1, wc = w & 1;
  const int m0 = blockIdx.x * 128, n0 = blockIdx.y * 128;

  const int r4 = lane >> 2;        // row within 16-row chunk
  const int c8 = (lane & 3) * 8;   // k-col (shorts)

  auto stage = [&](int buf, int k0) {
#pragma unroll
    for (int c = 0; c < 2; ++c) {
      const short* ag = A  + (size_t)(m0 + w * 32 + c * 16 + r4) * Kd + k0 + c8;
      const short* bg = BT + (size_t)(n0 + w * 32 + c * 16 + r4) * Kd + k0 + c8;
      __builtin_amdgcn_global_load_lds((gvoid_p)ag, (lvoid_p)&As[buf][(w * 2 + c) * 512], 16, 0, 0);
      __builtin_amdgcn_global_load_lds((gvoid_p)bg, (lvoid_p)&Bs[buf][(w * 2 + c) * 512], 16, 0, 0);
    }
  };

  f32x4 acc[4][4] = {};

  stage(0, 0);
  __syncthreads();  // vmcnt(0) drain: tile 0 ready

  const int NT = Kd / 32;
  for (int t = 0; t < NT; ++t) {
    const int cur = t & 1;
    if (t + 1 < NT) stage(cur ^ 1, (t + 1) * 32);  // in flight during compute

    short8 af[4], bfr[4];
#pragma unroll
    for (int mi = 0; mi < 4; ++mi)
      af[mi] = *(const short8*)&As[cur][(wr * 64 + mi * 16 + L) * 32 + g * 8];
#pragma unroll
    for (int ni = 0; ni < 4; ++ni)
      bfr[ni] = *(const short8*)&Bs[cur][(wc * 64 + ni * 16 + L) * 32 + g * 8];
#pragma unroll
    for (int mi = 0; mi < 4; ++mi)
#pragma unroll
      for (int ni = 0; ni < 4; ++ni)
        acc[mi][ni] = MFMA_B16(af[mi], bfr[ni], acc[mi][ni]);

    __syncthreads();  // drains vmcnt (prefetch landed) + lgkm; reuse-safe
  }

  if (EPI == 0) {
    const int t3 = n0 / kDim;  // 0:Q 1:K 2:V (uniform per block; 768 = 6*128)
#pragma unroll
    for (int mi = 0; mi < 4; ++mi) {
#pragma unroll
      for (int ni = 0; ni < 4; ++ni) {
        const int gcol = n0 + wc * 64 + ni * 16 + L;
        const int hd = gcol % kDim;
        const int h = hd >> 6, d = hd & 63;
        if (t3 == 2) {  // V^T: 4 r-values are contiguous seq -> one 8B store
          const int grow = m0 + wr * 64 + mi * 16 + 4 * g;
          const int b = grow >> 10, seq = grow & 1023;
          const int bh = b * kHeads + h;
          uint2 d2;
          d2.x = cvt_pk_bf16(acc[mi][ni][0], acc[mi][ni][1]);
          d2.y = cvt_pk_bf16(acc[mi][ni][2], acc[mi][ni][3]);
          *(uint2*)&VTb[((size_t)bh * 64 + d) * kSeq + seq] = d2;
        } else {
#pragma unroll
          for (int r = 0; r < 4; ++r) {
            const int grow = m0 + wr * 64 + mi * 16 + 4 * g + r;  // b*1024+seq
            const int b = grow >> 10, seq = grow & 1023;
            const int bh = b * kHeads + h;
            if (t3 == 0) Qb[((size_t)bh * kSeq + seq) * 64 + d] = f2bf(acc[mi][ni][r] * kQSc);
            else         Kb[((size_t)bh * kSeq + seq) * 64 + d] = f2bf(acc[mi][ni][r]);
          }
        }
      }
    }
  } else {
#pragma unroll
    for (int ni = 0; ni < 4; ++ni) {
      const int gcol = n0 + wc * 64 + ni * 16 + L;
      const float bv = bias[gcol];
#pragma unroll
      for (int mi = 0; mi < 4; ++mi) {
#pragma unroll
        for (int r = 0; r < 4; ++r) {
          const int grow = m0 + wr * 64 + mi * 16 + 4 * g + r;
          outF[(size_t)grow * kDim + gcol] = acc[mi][ni][r] + bv;
        }
      }
    }
  }
}

// ---------- flash attention v7 ----------------------------------------------
// R5 structure (K AND V staged in LDS, double-buffered, reg-staged T14 split,
// one barrier/tile; swapped QK^T + k-perm PV keeps P in registers; lazy
// max-reduce + deferred l-reduce). NEW vs R5: both q-halves' QK MFMA
// clusters issue back-to-back BEFORE softmax, so qh1's MFMA execution
// overlaps qh0's softmax VALU chain.
__global__ __launch_bounds__(256) void attn_kernel(const short* __restrict__ Qb,
                                                   const short* __restrict__ Kb,
                                                   const short* __restrict__ VTb,
                                                   short* __restrict__ AO) {
  __shared__ short Ks[2][64 * 72];   // [key][d]
  __shared__ short VTs[2][64 * 72];  // [d][key]

  const int tid  = threadIdx.x;
  const int lane = tid & 63, w = tid >> 6;
  const int L = lane & 15, g = lane >> 4;
  const int id = blockIdx.x;
  const int bh = id % 96, qc = id / 96;
  const int q0 = qc * 128 + w * 32;

  const short* Qbase = Qb  + (size_t)bh * kSeq * 64;
  const short* Kbase = Kb  + (size_t)bh * kSeq * 64;
  const short* Vbase = VTb + (size_t)bh * 64 * kSeq;

  short8 qf[2][2];  // Q (pre-scaled by kQSc) as B-operand, resident in regs
#pragma unroll
  for (int qh = 0; qh < 2; ++qh) {
    const short* qp = Qbase + (size_t)(q0 + qh * 16 + L) * 64 + g * 8;
    qf[qh][0] = *(const short8*)qp;
    qf[qh][1] = *(const short8*)(qp + 32);
  }

  f32x4 o[2][4] = {};
  float m_[2] = {-1e30f, -1e30f};  // per-query running max (replicated over g)
  float l_[2] = {0.f, 0.f};        // per-LANE partial sum (reduced at end)

  const int srow = tid >> 2, sc0 = (tid & 3) * 16;  // staging: 16 elems/thread

  {  // prologue: stage tile 0
    const short* ksrc = Kbase + (size_t)srow * 64 + sc0;
    const short* vsrc = Vbase + (size_t)srow * kSeq + sc0;
    uint4 k0 = ((const uint4*)ksrc)[0], k1 = ((const uint4*)ksrc)[1];
    uint4 v0 = ((const uint4*)vsrc)[0], v1 = ((const uint4*)vsrc)[1];
    *(uint4*)&Ks[0][srow * 72 + sc0]      = k0;
    *(uint4*)&Ks[0][srow * 72 + sc0 + 8]  = k1;
    *(uint4*)&VTs[0][srow * 72 + sc0]     = v0;
    *(uint4*)&VTs[0][srow * 72 + sc0 + 8] = v1;
  }
  __syncthreads();

  for (int t = 0; t < kSeq / 64; ++t) {
    const int cur = t & 1;
    const bool pf = (t + 1 < kSeq / 64);

    // ---- issue next-tile loads early (T14 async split) ----
    uint4 kr0, kr1, vr0, vr1;
    if (pf) {
      const int kv1 = (t + 1) * 64;
      const short* ksrc = Kbase + (size_t)(kv1 + srow) * 64 + sc0;
      const short* vsrc = Vbase + (size_t)srow * kSeq + kv1 + sc0;
      kr0 = ((const uint4*)ksrc)[0]; kr1 = ((const uint4*)ksrc)[1];
      vr0 = ((const uint4*)vsrc)[0]; vr1 = ((const uint4*)vsrc)[1];
    }

    // ---- K fragments (A-operand) + V fragments (k-perm B-operand) ----
    short8 kf[4][2];
#pragma unroll
    for (int nf = 0; nf < 4; ++nf) {
      const short* kp = &Ks[cur][(nf * 16 + L) * 72 + g * 8];
      kf[nf][0] = *(const short8*)kp;
      kf[nf][1] = *(const short8*)(kp + 32);
    }
    short8 vb[4][2];  // hoisted: ds latency hides under QK + softmax below
#pragma unroll
    for (int nf = 0; nf < 4; ++nf) {
      const short* vrow = &VTs[cur][(nf * 16 + L) * 72];
      s16x4 a0 = *(const s16x4*)&vrow[4 * g];
      s16x4 a1 = *(const s16x4*)&vrow[16 + 4 * g];
      s16x4 a2 = *(const s16x4*)&vrow[32 + 4 * g];
      s16x4 a3 = *(const s16x4*)&vrow[48 + 4 * g];
      vb[nf][0] = __builtin_shufflevector(a0, a1, 0, 1, 2, 3, 4, 5, 6, 7);
      vb[nf][1] = __builtin_shufflevector(a2, a3, 0, 1, 2, 3, 4, 5, 6, 7);
    }

    // ---- BOTH q-halves' S^T = K @ Q^T issued back-to-back (32 MFMAs) ----
    // qh1's MFMA execution latency hides under qh0's softmax below.
    f32x4 s2[2][4];
    __builtin_amdgcn_s_setprio(1);
#pragma unroll
    for (int qh = 0; qh < 2; ++qh) {
#pragma unroll
      for (int nf = 0; nf < 4; ++nf) {
        f32x4 z = {};
        z = MFMA_B16(kf[nf][0], qf[qh][0], z);
        s2[qh][nf] = MFMA_B16(kf[nf][1], qf[qh][1], z);
      }
    }
    __builtin_amdgcn_s_setprio(0);

    // ---- softmax per q-half (lazy max, per-lane l partial, P in regs) ----
    short8 pa[2][2];
#pragma unroll
    for (int qh = 0; qh < 2; ++qh) {
      f32x4* s = s2[qh];
      float x0 = fmaxf(fmaxf(s[0][0], s[0][1]), fmaxf(s[0][2], s[0][3]));
      float x1 = fmaxf(fmaxf(s[1][0], s[1][1]), fmaxf(s[1][2], s[1][3]));
      float x2 = fmaxf(fmaxf(s[2][0], s[2][1]), fmaxf(s[2][2], s[2][3]));
      float x3 = fmaxf(fmaxf(s[3][0], s[3][1]), fmaxf(s[3][2], s[3][3]));
      const float mt4 = fmaxf(fmaxf(x0, x1), fmaxf(x2, x3));

      if (__any(mt4 > m_[qh] + 8.0f)) {  // wave-uniform branch (rare)
        float mt = fmaxf(mt4, __shfl_xor(mt4, 16, 64));
        mt = fmaxf(mt, __shfl_xor(mt, 32, 64));          // per-query true max
        const float mnew = fmaxf(m_[qh], mt);
        const float al = __builtin_amdgcn_exp2f(m_[qh] - mnew);
        m_[qh] = mnew;
        l_[qh] *= al;  // per-lane partial: al is query-uniform across g
        float alr[4];
#pragma unroll
        for (int r = 0; r < 4; ++r) alr[r] = __shfl(al, 4 * g + r, 64);
#pragma unroll
        for (int nf = 0; nf < 4; ++nf)
#pragma unroll
          for (int r = 0; r < 4; ++r) o[qh][nf][r] *= alr[r];
      }

      float rsum = 0.f;
#pragma unroll
      for (int nf = 0; nf < 4; ++nf) {
#pragma unroll
        for (int r = 0; r < 4; ++r) {
          const float p = __builtin_amdgcn_exp2f(s[nf][r] - m_[qh]);
          s[nf][r] = p;
          rsum += p;
        }
      }
      l_[qh] += rsum;  // per-lane partial

      U8 t0, t1;
      t0.u[0] = cvt_pk_bf16(s[0][0], s[0][1]);
      t0.u[1] = cvt_pk_bf16(s[0][2], s[0][3]);
      t0.u[2] = cvt_pk_bf16(s[1][0], s[1][1]);
      t0.u[3] = cvt_pk_bf16(s[1][2], s[1][3]);
      t1.u[0] = cvt_pk_bf16(s[2][0], s[2][1]);
      t1.u[1] = cvt_pk_bf16(s[2][2], s[2][3]);
      t1.u[2] = cvt_pk_bf16(s[3][0], s[3][1]);
      t1.u[3] = cvt_pk_bf16(s[3][2], s[3][3]);
      pa[qh][0] = t0.s;
      pa[qh][1] = t1.s;
    }

    // ---- O += P @ V ----
    __builtin_amdgcn_s_setprio(1);
#pragma unroll
    for (int nf = 0; nf < 4; ++nf) {
#pragma unroll
      for (int qh = 0; qh < 2; ++qh) {
        o[qh][nf] = MFMA_B16(pa[qh][0], vb[nf][0], o[qh][nf]);
        o[qh][nf] = MFMA_B16(pa[qh][1], vb[nf][1], o[qh][nf]);
      }
    }
    __builtin_amdgcn_s_setprio(0);

    // ---- write prefetched tile into other buffer; one barrier per tile ----
    if (pf) {
      *(uint4*)&Ks[cur ^ 1][srow * 72 + sc0]      = kr0;
      *(uint4*)&Ks[cur ^ 1][srow * 72 + sc0 + 8]  = kr1;
      *(uint4*)&VTs[cur ^ 1][srow * 72 + sc0]     = vr0;
      *(uint4*)&VTs[cur ^ 1][srow * 72 + sc0 + 8] = vr1;
    }
    __syncthreads();
  }

  // ---- finalize: reduce l across g-groups ONCE, O /= l, store ----
  const int b = bh / kHeads, h = bh % kHeads;
#pragma unroll
  for (int qh = 0; qh < 2; ++qh) {
    float ls = l_[qh] + __shfl_xor(l_[qh], 16, 64);
    ls += __shfl_xor(ls, 32, 64);  // full per-query sum
    float lq[4];
#pragma unroll
    for (int r = 0; r < 4; ++r) lq[r] = __shfl(ls, 4 * g + r, 64);
    short* aop = AO + ((size_t)(b * kSeq) + q0 + qh * 16) * kDim + h * 64;
#pragma unroll
    for (int r = 0; r < 4; ++r) {
      const float inv = 1.0f / lq[r];
#pragma unroll
      for (int nf = 0; nf < 4; ++nf)
        aop[(size_t)(4 * g + r) * kDim + nf * 16 + L] = f2bf(o[qh][nf][r] * inv);
    }
  }
}

// ---------------------------------------------------------------------------
extern "C" void kernel_launch(void* const* d_in, const int* in_sizes, int n_in,
                              void* d_out, int out_size, void* d_ws, size_t ws_size,
                              hipStream_t stream) {
  const float* x     = (const float*)d_in[0];
  const float* w_in  = (const float*)d_in[1];
  const float* w_out = (const float*)d_in[2];
  const float* b_out = (const float*)d_in[3];
  float* out = (float*)d_out;

  // workspace (bf16 as short). xbf aliases AO: xbf dead before attn writes AO.
  short* WinT  = (short*)d_ws;                          // [2304][768]
  short* WoutT = WinT  + (size_t)2304 * 768;            // [768][768]
  short* Qb    = WoutT + (size_t)768 * 768;             // [96][1024][64]
  short* Kb    = Qb    + (size_t)96 * 1024 * 64;        // [96][1024][64]
  short* VTb   = Kb    + (size_t)96 * 1024 * 64;        // [96][64][1024]
  short* AO    = VTb   + (size_t)96 * 1024 * 64;        // [8192][768]
  short* xbf   = AO;                                    // alias (see above)

  cvt_f32_bf16<<<dim3(8192 * 768 / (256 * 8)), 256, 0, stream>>>(x, xbf);
  transpose_cvt<<<dim3(2304 / 32, 768 / 32), 256, 0, stream>>>(w_in, WinT, 768, 2304);
  transpose_cvt<<<dim3(768 / 32, 768 / 32), 256, 0, stream>>>(w_out, WoutT, 768, 768);

  gemm_tile<0><<<dim3(8192 / 128, 2304 / 128), 256, 0, stream>>>(
      xbf, WinT, 768, Qb, Kb, VTb, nullptr, nullptr);

  attn_kernel<<<dim3(768), 256, 0, stream>>>(Qb, Kb, VTb, AO);

  gemm_tile<1><<<dim3(8192 / 128, 768 / 128), 256, 0, stream>>>(
      AO, WoutT, 768, nullptr, nullptr, nullptr, b_out, out);
}

// Round 8
// 125.950 us; speedup vs baseline: 1.5976x; 1.0035x over previous
//
#include <hip/hip_runtime.h>

// ---------------------------------------------------------------------------
// MultiHeadedAttention: x[8,1024,768] @ w_in[768,2304] -> qkv -> 12-head attn
// (scale = 768^-0.5) -> concat -> @ w_out[768,768] + b_out. f32 in/out,
// bf16 MFMA internally. R8: GEMM main loop -> 3-buffer 2-deep prefetch with
// COUNTED vmcnt (T4): s_waitcnt vmcnt(8) + raw s_barrier instead of
// __syncthreads' vmcnt(0) drain; 8 loads stay in flight across barriers.
// Attn unchanged from R7.
// ---------------------------------------------------------------------------

using short8 = __attribute__((ext_vector_type(8))) short;  // 8 bf16 (4 VGPR)
using s16x4  = __attribute__((ext_vector_type(4))) short;  // 4 bf16 (b64)
using f32x4  = __attribute__((ext_vector_type(4))) float;  // MFMA acc

#define MFMA_B16(a, b, c) __builtin_amdgcn_mfma_f32_16x16x32_bf16((a), (b), (c), 0, 0, 0)

typedef const __attribute__((address_space(1))) void* gvoid_p;
typedef __attribute__((address_space(3))) void* lvoid_p;

constexpr int   kDim   = 768;
constexpr int   kHeads = 12;
constexpr int   kSeq   = 1024;
constexpr float kScale = 0.03608439182435161f;             // 768^-0.5 (full dim)
constexpr float kQSc   = kScale * 1.4426950408889634f;     // fold log2(e) into Q

__device__ __forceinline__ short f2bf(float f) {  // RNE f32 -> bf16 bits
  unsigned u = __float_as_uint(f);
  u += 0x7FFFu + ((u >> 16) & 1u);
  return (short)(u >> 16);
}
__device__ __forceinline__ unsigned cvt_pk_bf16(float lo, float hi) {
  unsigned r;
  asm("v_cvt_pk_bf16_f32 %0, %1, %2" : "=v"(r) : "v"(lo), "v"(hi));
  return r;
}
union U8 { unsigned u[4]; short8 s; };

// ---------- x: f32 -> bf16 cast ---------------------------------------------
__global__ __launch_bounds__(256) void cvt_f32_bf16(const float* __restrict__ in,
                                                    short* __restrict__ out) {
  const int i = blockIdx.x * 256 + threadIdx.x;  // one short8 per thread
  float4 a = ((const float4*)in)[i * 2];
  float4 b = ((const float4*)in)[i * 2 + 1];
  short8 s;
  s[0] = f2bf(a.x); s[1] = f2bf(a.y); s[2] = f2bf(a.z); s[3] = f2bf(a.w);
  s[4] = f2bf(b.x); s[5] = f2bf(b.y); s[6] = f2bf(b.z); s[7] = f2bf(b.w);
  ((short8*)out)[i] = s;
}

// ---------- transpose + convert: out[c][r] = bf16(in[r][c]) ----------------
__global__ __launch_bounds__(256) void transpose_cvt(const float* __restrict__ in,
                                                     short* __restrict__ out,
                                                     int R, int C) {
  __shared__ float tile[32][33];
  const int c0 = blockIdx.x * 32, r0 = blockIdx.y * 32;
  const int tx = threadIdx.x & 31, ty = threadIdx.x >> 5;
#pragma unroll
  for (int i = 0; i < 32; i += 8)
    tile[ty + i][tx] = in[(size_t)(r0 + ty + i) * C + c0 + tx];
  __syncthreads();
#pragma unroll
  for (int i = 0; i < 32; i += 8)
    out[(size_t)(c0 + ty + i) * R + r0 + tx] = f2bf(tile[tx][ty + i]);
}

// ---------- 128x128 MFMA GEMM, BK=32, 4 waves, 3-buf 2-deep counted-vmcnt --
// Per K-step: stage(t+2) -> vmcnt(8) [tile t landed, 8 newer in flight] ->
// s_barrier -> ds_read+MFMA(buf t%3) -> s_barrier [reads done before the
// next iteration's stage overwrites this buffer]. No vmcnt(0) in the loop.
template <int EPI>
__global__ __launch_bounds__(256) void gemm_tile(const short* __restrict__ A,
                                                 const short* __restrict__ BT,
                                                 int Kd,
                                                 short* __restrict__ Qb,
                                                 short* __restrict__ Kb,
                                                 short* __restrict__ VTb,
                                                 const float* __restrict__ bias,
                                                 float* __restrict__ outF) {
  __shared__ short As[3][128 * 32];
  __shared__ short Bs[3][128 * 32];

  const int tid  = threadIdx.x;
  const int lane = tid & 63, w = tid >> 6;
  const int L = lane & 15, g = lane >> 4;
  const int wr = w >> 1, wc = w & 1;
  const int m0 = blockIdx.x * 128, n0 = blockIdx.y * 128;

  const int r4 = lane >> 2;        // row within 16-row chunk
  const int c8 = (lane & 3) * 8;   // k-col (shorts)

  auto stage = [&](int buf, int k0) {  // 4 gload_lds per wave (vmcnt +4)
#pragma unroll
    for (int c = 0; c < 2; ++c) {
      const short* ag = A  + (size_t)(m0 + w * 32 + c * 16 + r4) * Kd + k0 + c8;
      const short* bg = BT + (size_t)(n0 + w * 32 + c * 16 + r4) * Kd + k0 + c8;
      __builtin_amdgcn_global_load_lds((gvoid_p)ag, (lvoid_p)&As[buf][(w * 2 + c) * 512], 16, 0, 0);
      __builtin_amdgcn_global_load_lds((gvoid_p)bg, (lvoid_p)&Bs[buf][(w * 2 + c) * 512], 16, 0, 0);
    }
  };

  f32x4 acc[4][4] = {};

  stage(0, 0);
  stage(1, 32);

  const int NT = Kd / 32;
  for (int t = 0; t < NT; ++t) {
    const int cur = t % 3;
    if (t + 2 < NT) stage((t + 2) % 3, (t + 2) * 32);

    // wait for tile t only; tiles t+1, t+2 (8 loads) stay in flight
    if (t + 2 < NT)      asm volatile("s_waitcnt vmcnt(8)" ::: "memory");
    else if (t + 1 < NT) asm volatile("s_waitcnt vmcnt(4)" ::: "memory");
    else                 asm volatile("s_waitcnt vmcnt(0)" ::: "memory");
    __builtin_amdgcn_s_barrier();  // all waves' tile-t loads landed

    short8 af[4], bfr[4];
#pragma unroll
    for (int mi = 0; mi < 4; ++mi)
      af[mi] = *(const short8*)&As[cur][(wr * 64 + mi * 16 + L) * 32 + g * 8];
#pragma unroll
    for (int ni = 0; ni < 4; ++ni)
      bfr[ni] = *(const short8*)&Bs[cur][(wc * 64 + ni * 16 + L) * 32 + g * 8];
#pragma unroll
    for (int mi = 0; mi < 4; ++mi)
#pragma unroll
      for (int ni = 0; ni < 4; ++ni)
        acc[mi][ni] = MFMA_B16(af[mi], bfr[ni], acc[mi][ni]);

    // reads of buf[cur] consumed (lgkm waits precede the MFMAs); fence the
    // compiler, then barrier so no wave's NEXT stage overwrites buf[cur]
    // while another wave still reads it.
    asm volatile("" ::: "memory");
    __builtin_amdgcn_s_barrier();
  }

  if (EPI == 0) {
    const int t3 = n0 / kDim;  // 0:Q 1:K 2:V (uniform per block; 768 = 6*128)
#pragma unroll
    for (int mi = 0; mi < 4; ++mi) {
#pragma unroll
      for (int ni = 0; ni < 4; ++ni) {
        const int gcol = n0 + wc * 64 + ni * 16 + L;
        const int hd = gcol % kDim;
        const int h = hd >> 6, d = hd & 63;
        if (t3 == 2) {  // V^T: 4 r-values are contiguous seq -> one 8B store
          const int grow = m0 + wr * 64 + mi * 16 + 4 * g;
          const int b = grow >> 10, seq = grow & 1023;
          const int bh = b * kHeads + h;
          uint2 d2;
          d2.x = cvt_pk_bf16(acc[mi][ni][0], acc[mi][ni][1]);
          d2.y = cvt_pk_bf16(acc[mi][ni][2], acc[mi][ni][3]);
          *(uint2*)&VTb[((size_t)bh * 64 + d) * kSeq + seq] = d2;
        } else {
#pragma unroll
          for (int r = 0; r < 4; ++r) {
            const int grow = m0 + wr * 64 + mi * 16 + 4 * g + r;  // b*1024+seq
            const int b = grow >> 10, seq = grow & 1023;
            const int bh = b * kHeads + h;
            if (t3 == 0) Qb[((size_t)bh * kSeq + seq) * 64 + d] = f2bf(acc[mi][ni][r] * kQSc);
            else         Kb[((size_t)bh * kSeq + seq) * 64 + d] = f2bf(acc[mi][ni][r]);
          }
        }
      }
    }
  } else {
#pragma unroll
    for (int ni = 0; ni < 4; ++ni) {
      const int gcol = n0 + wc * 64 + ni * 16 + L;
      const float bv = bias[gcol];
#pragma unroll
      for (int mi = 0; mi < 4; ++mi) {
#pragma unroll
        for (int r = 0; r < 4; ++r) {
          const int grow = m0 + wr * 64 + mi * 16 + 4 * g + r;
          outF[(size_t)grow * kDim + gcol] = acc[mi][ni][r] + bv;
        }
      }
    }
  }
}

// ---------- flash attention (R7, unchanged) ---------------------------------
__global__ __launch_bounds__(256) void attn_kernel(const short* __restrict__ Qb,
                                                   const short* __restrict__ Kb,
                                                   const short* __restrict__ VTb,
                                                   short* __restrict__ AO) {
  __shared__ short Ks[2][64 * 72];   // [key][d]
  __shared__ short VTs[2][64 * 72];  // [d][key]

  const int tid  = threadIdx.x;
  const int lane = tid & 63, w = tid >> 6;
  const int L = lane & 15, g = lane >> 4;
  const int id = blockIdx.x;
  const int bh = id % 96, qc = id / 96;
  const int q0 = qc * 128 + w * 32;

  const short* Qbase = Qb  + (size_t)bh * kSeq * 64;
  const short* Kbase = Kb  + (size_t)bh * kSeq * 64;
  const short* Vbase = VTb + (size_t)bh * 64 * kSeq;

  short8 qf[2][2];  // Q (pre-scaled by kQSc) as B-operand, resident in regs
#pragma unroll
  for (int qh = 0; qh < 2; ++qh) {
    const short* qp = Qbase + (size_t)(q0 + qh * 16 + L) * 64 + g * 8;
    qf[qh][0] = *(const short8*)qp;
    qf[qh][1] = *(const short8*)(qp + 32);
  }

  f32x4 o[2][4] = {};
  float m_[2] = {-1e30f, -1e30f};  // per-query running max (replicated over g)
  float l_[2] = {0.f, 0.f};        // per-LANE partial sum (reduced at end)

  const int srow = tid >> 2, sc0 = (tid & 3) * 16;  // staging: 16 elems/thread

  {  // prologue: stage tile 0
    const short* ksrc = Kbase + (size_t)srow * 64 + sc0;
    const short* vsrc = Vbase + (size_t)srow * kSeq + sc0;
    uint4 k0 = ((const uint4*)ksrc)[0], k1 = ((const uint4*)ksrc)[1];
    uint4 v0 = ((const uint4*)vsrc)[0], v1 = ((const uint4*)vsrc)[1];
    *(uint4*)&Ks[0][srow * 72 + sc0]      = k0;
    *(uint4*)&Ks[0][srow * 72 + sc0 + 8]  = k1;
    *(uint4*)&VTs[0][srow * 72 + sc0]     = v0;
    *(uint4*)&VTs[0][srow * 72 + sc0 + 8] = v1;
  }
  __syncthreads();

  for (int t = 0; t < kSeq / 64; ++t) {
    const int cur = t & 1;
    const bool pf = (t + 1 < kSeq / 64);

    // ---- issue next-tile loads early (T14 async split) ----
    uint4 kr0, kr1, vr0, vr1;
    if (pf) {
      const int kv1 = (t + 1) * 64;
      const short* ksrc = Kbase + (size_t)(kv1 + srow) * 64 + sc0;
      const short* vsrc = Vbase + (size_t)srow * kSeq + kv1 + sc0;
      kr0 = ((const uint4*)ksrc)[0]; kr1 = ((const uint4*)ksrc)[1];
      vr0 = ((const uint4*)vsrc)[0]; vr1 = ((const uint4*)vsrc)[1];
    }

    // ---- K fragments (A-operand) + V fragments (k-perm B-operand) ----
    short8 kf[4][2];
#pragma unroll
    for (int nf = 0; nf < 4; ++nf) {
      const short* kp = &Ks[cur][(nf * 16 + L) * 72 + g * 8];
      kf[nf][0] = *(const short8*)kp;
      kf[nf][1] = *(const short8*)(kp + 32);
    }
    short8 vb[4][2];  // hoisted: ds latency hides under QK + softmax below
#pragma unroll
    for (int nf = 0; nf < 4; ++nf) {
      const short* vrow = &VTs[cur][(nf * 16 + L) * 72];
      s16x4 a0 = *(const s16x4*)&vrow[4 * g];
      s16x4 a1 = *(const s16x4*)&vrow[16 + 4 * g];
      s16x4 a2 = *(const s16x4*)&vrow[32 + 4 * g];
      s16x4 a3 = *(const s16x4*)&vrow[48 + 4 * g];
      vb[nf][0] = __builtin_shufflevector(a0, a1, 0, 1, 2, 3, 4, 5, 6, 7);
      vb[nf][1] = __builtin_shufflevector(a2, a3, 0, 1, 2, 3, 4, 5, 6, 7);
    }

    // ---- BOTH q-halves' S^T = K @ Q^T issued back-to-back (32 MFMAs) ----
    f32x4 s2[2][4];
    __builtin_amdgcn_s_setprio(1);
#pragma unroll
    for (int qh = 0; qh < 2; ++qh) {
#pragma unroll
      for (int nf = 0; nf < 4; ++nf) {
        f32x4 z = {};
        z = MFMA_B16(kf[nf][0], qf[qh][0], z);
        s2[qh][nf] = MFMA_B16(kf[nf][1], qf[qh][1], z);
      }
    }
    __builtin_amdgcn_s_setprio(0);

    // ---- softmax per q-half (lazy max, per-lane l partial, P in regs) ----
    short8 pa[2][2];
#pragma unroll
    for (int qh = 0; qh < 2; ++qh) {
      f32x4* s = s2[qh];
      float x0 = fmaxf(fmaxf(s[0][0], s[0][1]), fmaxf(s[0][2], s[0][3]));
      float x1 = fmaxf(fmaxf(s[1][0], s[1][1]), fmaxf(s[1][2], s[1][3]));
      float x2 = fmaxf(fmaxf(s[2][0], s[2][1]), fmaxf(s[2][2], s[2][3]));
      float x3 = fmaxf(fmaxf(s[3][0], s[3][1]), fmaxf(s[3][2], s[3][3]));
      const float mt4 = fmaxf(fmaxf(x0, x1), fmaxf(x2, x3));

      if (__any(mt4 > m_[qh] + 8.0f)) {  // wave-uniform branch (rare)
        float mt = fmaxf(mt4, __shfl_xor(mt4, 16, 64));
        mt = fmaxf(mt, __shfl_xor(mt, 32, 64));          // per-query true max
        const float mnew = fmaxf(m_[qh], mt);
        const float al = __builtin_amdgcn_exp2f(m_[qh] - mnew);
        m_[qh] = mnew;
        l_[qh] *= al;  // per-lane partial: al is query-uniform across g
        float alr[4];
#pragma unroll
        for (int r = 0; r < 4; ++r) alr[r] = __shfl(al, 4 * g + r, 64);
#pragma unroll
        for (int nf = 0; nf < 4; ++nf)
#pragma unroll
          for (int r = 0; r < 4; ++r) o[qh][nf][r] *= alr[r];
      }

      float rsum = 0.f;
#pragma unroll
      for (int nf = 0; nf < 4; ++nf) {
#pragma unroll
        for (int r = 0; r < 4; ++r) {
          const float p = __builtin_amdgcn_exp2f(s[nf][r] - m_[qh]);
          s[nf][r] = p;
          rsum += p;
        }
      }
      l_[qh] += rsum;  // per-lane partial

      U8 t0, t1;
      t0.u[0] = cvt_pk_bf16(s[0][0], s[0][1]);
      t0.u[1] = cvt_pk_bf16(s[0][2], s[0][3]);
      t0.u[2] = cvt_pk_bf16(s[1][0], s[1][1]);
      t0.u[3] = cvt_pk_bf16(s[1][2], s[1][3]);
      t1.u[0] = cvt_pk_bf16(s[2][0], s[2][1]);
      t1.u[1] = cvt_pk_bf16(s[2][2], s[2][3]);
      t1.u[2] = cvt_pk_bf16(s[3][0], s[3][1]);
      t1.u[3] = cvt_pk_bf16(s[3][2], s[3][3]);
      pa[qh][0] = t0.s;
      pa[qh][1] = t1.s;
    }

    // ---- O += P @ V ----
    __builtin_amdgcn_s_setprio(1);
#pragma unroll
    for (int nf = 0; nf < 4; ++nf) {
#pragma unroll
      for (int qh = 0; qh < 2; ++qh) {
        o[qh][nf] = MFMA_B16(pa[qh][0], vb[nf][0], o[qh][nf]);
        o[qh][nf] = MFMA_B16(pa[qh][1], vb[nf][1], o[qh][nf]);
      }
    }
    __builtin_amdgcn_s_setprio(0);

    // ---- write prefetched tile into other buffer; one barrier per tile ----
    if (pf) {
      *(uint4*)&Ks[cur ^ 1][srow * 72 + sc0]      = kr0;
      *(uint4*)&Ks[cur ^ 1][srow * 72 + sc0 + 8]  = kr1;
      *(uint4*)&VTs[cur ^ 1][srow * 72 + sc0]     = vr0;
      *(uint4*)&VTs[cur ^ 1][srow * 72 + sc0 + 8] = vr1;
    }
    __syncthreads();
  }

  // ---- finalize: reduce l across g-groups ONCE, O /= l, store ----
  const int b = bh / kHeads, h = bh % kHeads;
#pragma unroll
  for (int qh = 0; qh < 2; ++qh) {
    float ls = l_[qh] + __shfl_xor(l_[qh], 16, 64);
    ls += __shfl_xor(ls, 32, 64);  // full per-query sum
    float lq[4];
#pragma unroll
    for (int r = 0; r < 4; ++r) lq[r] = __shfl(ls, 4 * g + r, 64);
    short* aop = AO + ((size_t)(b * kSeq) + q0 + qh * 16) * kDim + h * 64;
#pragma unroll
    for (int r = 0; r < 4; ++r) {
      const float inv = 1.0f / lq[r];
#pragma unroll
      for (int nf = 0; nf < 4; ++nf)
        aop[(size_t)(4 * g + r) * kDim + nf * 16 + L] = f2bf(o[qh][nf][r] * inv);
    }
  }
}

// ---------------------------------------------------------------------------
extern "C" void kernel_launch(void* const* d_in, const int* in_sizes, int n_in,
                              void* d_out, int out_size, void* d_ws, size_t ws_size,
                              hipStream_t stream) {
  const float* x     = (const float*)d_in[0];
  const float* w_in  = (const float*)d_in[1];
  const float* w_out = (const float*)d_in[2];
  const float* b_out = (const float*)d_in[3];
  float* out = (float*)d_out;

  // workspace (bf16 as short). xbf aliases AO: xbf dead before attn writes AO.
  short* WinT  = (short*)d_ws;                          // [2304][768]
  short* WoutT = WinT  + (size_t)2304 * 768;            // [768][768]
  short* Qb    = WoutT + (size_t)768 * 768;             // [96][1024][64]
  short* Kb    = Qb    + (size_t)96 * 1024 * 64;        // [96][1024][64]
  short* VTb   = Kb    + (size_t)96 * 1024 * 64;        // [96][64][1024]
  short* AO    = VTb   + (size_t)96 * 1024 * 64;        // [8192][768]
  short* xbf   = AO;                                    // alias (see above)

  cvt_f32_bf16<<<dim3(8192 * 768 / (256 * 8)), 256, 0, stream>>>(x, xbf);
  transpose_cvt<<<dim3(2304 / 32, 768 / 32), 256, 0, stream>>>(w_in, WinT, 768, 2304);
  transpose_cvt<<<dim3(768 / 32, 768 / 32), 256, 0, stream>>>(w_out, WoutT, 768, 768);

  gemm_tile<0><<<dim3(8192 / 128, 2304 / 128), 256, 0, stream>>>(
      xbf, WinT, 768, Qb, Kb, VTb, nullptr, nullptr);

  attn_kernel<<<dim3(768), 256, 0, stream>>>(Qb, Kb, VTb, AO);

  gemm_tile<1><<<dim3(8192 / 128, 768 / 128), 256, 0, stream>>>(
      AO, WoutT, 768, nullptr, nullptr, nullptr, b_out, out);
}